// Round 1
// baseline (28.934 us; speedup 1.0000x reference)
//
#include <hip/hip_runtime.h>

// SiameseLoss: 32768 pairs of 512-d fp32 rows.
//   differ: sum((x1-x2)^2)      same: relu(1 - sqrt(sum((x1-x2*x2)^2)))
//   out = sum(per_pair) / 131072
// Memory-bound: 128 MiB read. Wave-per-pair, float4 coalesced loads.

constexpr int HALF    = 32768;
constexpr int D       = 512;
constexpr int NBLOCKS = 2048;
constexpr int THREADS = 256;
constexpr int WPB     = THREADS / 64;          // waves per block = 4
constexpr int NWAVES  = NBLOCKS * WPB;         // 8192

__global__ __launch_bounds__(THREADS) void siamese_partial(
    const float* __restrict__ x, const int* __restrict__ label,
    float* __restrict__ partials) {
  const int lane  = threadIdx.x & 63;
  const int wave  = threadIdx.x >> 6;
  const int gwave = blockIdx.x * WPB + wave;

  float acc = 0.0f;
  for (int p = gwave; p < HALF; p += NWAVES) {
    const float4* a = reinterpret_cast<const float4*>(x + (size_t)p * D);
    const float4* b = reinterpret_cast<const float4*>(x + (size_t)(HALF + p) * D);
    float sd  = 0.0f;   // sum (x1-x2)^2
    float sd2 = 0.0f;   // sum (x1-x2*x2)^2
#pragma unroll
    for (int k = 0; k < 2; ++k) {
      float4 va = a[lane + 64 * k];
      float4 vb = b[lane + 64 * k];
      float dx = va.x - vb.x, dy = va.y - vb.y;
      float dz = va.z - vb.z, dw = va.w - vb.w;
      sd = fmaf(dx, dx, sd); sd = fmaf(dy, dy, sd);
      sd = fmaf(dz, dz, sd); sd = fmaf(dw, dw, sd);
      float ex = fmaf(-vb.x, vb.x, va.x);
      float ey = fmaf(-vb.y, vb.y, va.y);
      float ez = fmaf(-vb.z, vb.z, va.z);
      float ew = fmaf(-vb.w, vb.w, va.w);
      sd2 = fmaf(ex, ex, sd2); sd2 = fmaf(ey, ey, sd2);
      sd2 = fmaf(ez, ez, sd2); sd2 = fmaf(ew, ew, sd2);
    }
    // 64-lane butterfly reduce of both sums
#pragma unroll
    for (int m = 32; m >= 1; m >>= 1) {
      sd  += __shfl_xor(sd,  m);
      sd2 += __shfl_xor(sd2, m);
    }
    if (lane == 0) {
      bool differ = label[p] != label[HALF + p];
      acc += differ ? sd : fmaxf(0.0f, 1.0f - sqrtf(sd2));
    }
  }

  __shared__ float lds[WPB];
  if (lane == 0) lds[wave] = acc;
  __syncthreads();
  if (threadIdx.x == 0) {
    float s = 0.0f;
#pragma unroll
    for (int w = 0; w < WPB; ++w) s += lds[w];
    partials[blockIdx.x] = s;
  }
}

__global__ __launch_bounds__(256) void siamese_reduce(
    const float* __restrict__ partials, float* __restrict__ out) {
  float s = 0.0f;
  for (int i = threadIdx.x; i < NBLOCKS; i += 256) s += partials[i];
#pragma unroll
  for (int m = 32; m >= 1; m >>= 1) s += __shfl_xor(s, m);
  __shared__ float lds[4];
  if ((threadIdx.x & 63) == 0) lds[threadIdx.x >> 6] = s;
  __syncthreads();
  if (threadIdx.x == 0) {
    float t = lds[0] + lds[1] + lds[2] + lds[3];
    out[0] = t * (1.0f / (float)(HALF * 4));
  }
}

extern "C" void kernel_launch(void* const* d_in, const int* in_sizes, int n_in,
                              void* d_out, int out_size, void* d_ws, size_t ws_size,
                              hipStream_t stream) {
  const float* x     = (const float*)d_in[0];
  const int*   label = (const int*)d_in[1];
  float* out      = (float*)d_out;
  float* partials = (float*)d_ws;   // NBLOCKS floats, fully rewritten each call

  siamese_partial<<<NBLOCKS, THREADS, 0, stream>>>(x, label, partials);
  siamese_reduce<<<1, 256, 0, stream>>>(partials, out);
}

// Round 2
// 28.510 us; speedup vs baseline: 1.0149x; 1.0149x over previous
//
#include <hip/hip_runtime.h>

// SiameseLoss: 32768 pairs of 512-d fp32 rows.
//   differ: sum((x1-x2)^2)      same: relu(1 - sqrt(sum((x1-x2*x2)^2)))
//   out = sum(per_pair) / 131072
// Memory-bound: 128 MiB read. Wave-per-pair, float4 coalesced loads.
// Key structure: labels are wave-uniform per pair, and P(same)~1/1000, so the
// common "differ" path accumulates per-LANE (no cross-lane reduce per pair);
// only rare "same" pairs pay the 6-step shuffle reduce. One wave reduce at end.

constexpr int HALF    = 32768;
constexpr int D       = 512;
constexpr int NBLOCKS = 2048;
constexpr int THREADS = 256;
constexpr int WPB     = THREADS / 64;          // waves per block = 4
constexpr int NWAVES  = NBLOCKS * WPB;         // 8192
constexpr int PPW     = HALF / NWAVES;         // pairs per wave = 4 (exact)

__global__ __launch_bounds__(THREADS) void siamese_partial(
    const float* __restrict__ x, const int* __restrict__ label,
    float* __restrict__ partials) {
  const int lane  = threadIdx.x & 63;
  const int wave  = threadIdx.x >> 6;
  const int gwave = blockIdx.x * WPB + wave;

  float acc = 0.0f;   // per-lane accumulator (mixed: lane partials of sd, plus
                      // loss_same terms folded in at lane 0)
#pragma unroll
  for (int i = 0; i < PPW; ++i) {
    const int p = gwave + i * NWAVES;
    const float4* a = reinterpret_cast<const float4*>(x + (size_t)p * D);
    const float4* b = reinterpret_cast<const float4*>(x + (size_t)(HALF + p) * D);
    // Issue all data loads up front (needed by either branch).
    float4 a0 = a[lane];
    float4 a1 = a[lane + 64];
    float4 b0 = b[lane];
    float4 b1 = b[lane + 64];
    const int l1 = label[p];
    const int l2 = label[HALF + p];

    if (l1 != l2) {
      // differ: per-lane accumulate sum((x1-x2)^2); no cross-lane work.
      float dx = a0.x - b0.x, dy = a0.y - b0.y, dz = a0.z - b0.z, dw = a0.w - b0.w;
      acc = fmaf(dx, dx, acc); acc = fmaf(dy, dy, acc);
      acc = fmaf(dz, dz, acc); acc = fmaf(dw, dw, acc);
      dx = a1.x - b1.x; dy = a1.y - b1.y; dz = a1.z - b1.z; dw = a1.w - b1.w;
      acc = fmaf(dx, dx, acc); acc = fmaf(dy, dy, acc);
      acc = fmaf(dz, dz, acc); acc = fmaf(dw, dw, acc);
    } else {
      // same (rare ~1/1000): need per-pair sqrt(sum((x1-x2*x2)^2)).
      float ex = fmaf(-b0.x, b0.x, a0.x);
      float ey = fmaf(-b0.y, b0.y, a0.y);
      float ez = fmaf(-b0.z, b0.z, a0.z);
      float ew = fmaf(-b0.w, b0.w, a0.w);
      float sd2 = ex * ex;
      sd2 = fmaf(ey, ey, sd2); sd2 = fmaf(ez, ez, sd2); sd2 = fmaf(ew, ew, sd2);
      ex = fmaf(-b1.x, b1.x, a1.x);
      ey = fmaf(-b1.y, b1.y, a1.y);
      ez = fmaf(-b1.z, b1.z, a1.z);
      ew = fmaf(-b1.w, b1.w, a1.w);
      sd2 = fmaf(ex, ex, sd2); sd2 = fmaf(ey, ey, sd2);
      sd2 = fmaf(ez, ez, sd2); sd2 = fmaf(ew, ew, sd2);
#pragma unroll
      for (int m = 32; m >= 1; m >>= 1) sd2 += __shfl_xor(sd2, m);
      if (lane == 0) acc += fmaxf(0.0f, 1.0f - sqrtf(sd2));
    }
  }

  // One wave reduce at the end.
#pragma unroll
  for (int m = 32; m >= 1; m >>= 1) acc += __shfl_xor(acc, m);

  __shared__ float lds[WPB];
  if (lane == 0) lds[wave] = acc;
  __syncthreads();
  if (threadIdx.x == 0) {
    float s = 0.0f;
#pragma unroll
    for (int w = 0; w < WPB; ++w) s += lds[w];
    partials[blockIdx.x] = s;
  }
}

__global__ __launch_bounds__(256) void siamese_reduce(
    const float* __restrict__ partials, float* __restrict__ out) {
  float s = 0.0f;
  for (int i = threadIdx.x; i < NBLOCKS; i += 256) s += partials[i];
#pragma unroll
  for (int m = 32; m >= 1; m >>= 1) s += __shfl_xor(s, m);
  __shared__ float lds[4];
  if ((threadIdx.x & 63) == 0) lds[threadIdx.x >> 6] = s;
  __syncthreads();
  if (threadIdx.x == 0) {
    float t = lds[0] + lds[1] + lds[2] + lds[3];
    out[0] = t * (1.0f / (float)(HALF * 4));
  }
}

extern "C" void kernel_launch(void* const* d_in, const int* in_sizes, int n_in,
                              void* d_out, int out_size, void* d_ws, size_t ws_size,
                              hipStream_t stream) {
  const float* x     = (const float*)d_in[0];
  const int*   label = (const int*)d_in[1];
  float* out      = (float*)d_out;
  float* partials = (float*)d_ws;   // NBLOCKS floats, fully rewritten each call

  siamese_partial<<<NBLOCKS, THREADS, 0, stream>>>(x, label, partials);
  siamese_reduce<<<1, 256, 0, stream>>>(partials, out);
}